// Round 15
// baseline (145.181 us; speedup 1.0000x reference)
//
#include <hip/hip_runtime.h>
#include <cstdint>

#define NB 64
#define NC 256
#define ND 256
#define NT 4096

// ---- main (ws) kernel geometry ----
#define BT 32                     // t per tile
#define NTILES 8                  // tiles per block
#define CHUNK (BT * NTILES)       // 256 t per block
#define NCHUNK (NT / CHUNK)       // 16 -> grid (16,64) = 1024 blocks ~ 4/CU

typedef __attribute__((ext_vector_type(8)))  _Float16 half8;
typedef __attribute__((ext_vector_type(16))) float    f32x16;

union FragA { uint32_t u[4]; uint4 q; half8 v; };

__device__ __forceinline__ uint32_t pk_f16(float lo, float hi) {
    // v_cvt_pkrtz_f16_f32: D.lo=f16(lo), D.hi=f16(hi) — MFMA (k even, k odd) packing
    return __builtin_bit_cast(uint32_t, __builtin_amdgcn_cvt_pkrtz(lo, hi));
}

// ---------------------------------------------------------------------------
// Prep: W -> frag-ordered fp16 in d_ws.  For (s, wd, ks): 64 lanes x uint4
// (= half8 = the exact A-operand fragment of mfma_f32_32x32x16_f16 for
// d-slice wd: lane&31 = d, k(c) = 8*(lane>>5)+j).  4 MB total (S=32).
// Main kernel then loads W as ONE coalesced 16B/lane load per K-step from
// L2 instead of holding 64 VGPRs/wave — the occupancy ceiling since R1.
// ---------------------------------------------------------------------------
__global__ void wprep(const float* __restrict__ w, uint4* __restrict__ wsf) {
    const int lane = threadIdx.x;          // 64
    const int wd   = blockIdx.x;           // 0..7 d-slice
    const int s    = blockIdx.y;           // subject
    const int g    = lane >> 5;
    const int l31  = lane & 31;
    const float* wsub = w + (size_t)s * NC * ND;
    const int dlane = wd * 32 + l31;
#pragma unroll
    for (int ks = 0; ks < 16; ++ks) {
        float f[8];
#pragma unroll
        for (int j = 0; j < 8; ++j)
            f[j] = wsub[(size_t)(ks * 16 + g * 8 + j) * ND + dlane];
        uint4 q;
        q.x = pk_f16(f[0], f[1]); q.y = pk_f16(f[2], f[3]);
        q.z = pk_f16(f[4], f[5]); q.w = pk_f16(f[6], f[7]);
        wsf[(size_t)(((s * 8 + wd) * 16 + ks) * 64) + lane] = q;
    }
}

// ---------------------------------------------------------------------------
// Main: no W regs, no stage regs.  x staged fp32 via global_load_lds into a
// SINGLE 32 KB buffer [c=0..255][t=0..31] (row 128 B, linear dest + per-lane
// source per rule 21; write = lane*16B contiguous, read = 32 consecutive
// floats/half-wave -> both conflict-free).  2 barriers/tile; concurrency
// comes from 4 independent blocks/CU (launch_bounds(512,8) -> <=64 regs).
// MFMA: D[m=d][n=t]; A = W frag (from d_ws), B = x frag (lane&31=t).
// C/D: col = lane&31 = t -> coalesced 4B/lane stores.
// ---------------------------------------------------------------------------
__global__ __launch_bounds__(512, 8)
void subject_gemm_ws(const float* __restrict__ x,
                     const int*   __restrict__ subjects,
                     const uint4* __restrict__ wsf,
                     float*       __restrict__ out)
{
    __shared__ __align__(16) unsigned char lds[32 * 1024];  // fp32 x-tile [c][t]

    const int tid  = threadIdx.x;
    const int lane = tid & 63;
    const int wv   = tid >> 6;      // 0..7 : d-subtile
    const int g    = lane >> 5;
    const int l31  = lane & 31;     // t (B-frag), d-within-slice (A)
    const int b    = blockIdx.y;
    const int t0   = blockIdx.x * CHUNK;

    const int sub = subjects[b];
    const float* __restrict__ xb = x + (size_t)b * NC * NT;
    float*       __restrict__ ob = out + (size_t)b * ND * NT;

    // this wave's W-frag base in d_ws (ks stride = 1024 B); lane-varying -> VGPR
    const uint4* wa = wsf + (size_t)((sub * 8 + wv) * 16) * 64 + lane;

    // staging share: wave issues 4 x 1KB global_load_lds; instr q = wv*4+ii
    // covers LDS [q*8 .. q*8+7][0..31]; lane: c = q*8 + (lane>>3), tq = lane&7
    const int stq = lane >> 3;
    const int ttq = (lane & 7) * 4;

    for (int tile = 0; tile < NTILES; ++tile) {
        const int tg = t0 + tile * BT;

        __syncthreads();   // all waves done reading previous tile's buffer

#pragma unroll
        for (int ii = 0; ii < 4; ++ii) {
            const int q = wv * 4 + ii;
            const float* src = xb + (size_t)(q * 8 + stq) * NT + tg + ttq;
            __builtin_amdgcn_global_load_lds(
                (const __attribute__((address_space(1))) void*)src,
                (__attribute__((address_space(3))) void*)&lds[q * 1024],
                16, 0, 0);
        }

        __syncthreads();   // vmcnt(0) drain: tile resident for all waves

        const uint4* wt = wa;
        asm volatile("" : "+v"(wt));   // CSE-blind (VGPR constraint — lane-varying):
                                       // forbids hoisting W loads into persistent regs

        f32x16 acc = {};
#pragma unroll
        for (int ks = 0; ks < 16; ++ks) {
            FragA wf;
            wf.q = wt[(size_t)ks * 64];    // L2-resident frag, 16B/lane coalesced
            FragA a;
#pragma unroll
            for (int p = 0; p < 4; ++p) {
                const float lo = *(const float*)&lds[(ks * 16 + g * 8 + 2 * p    ) * 128 + l31 * 4];
                const float hi = *(const float*)&lds[(ks * 16 + g * 8 + 2 * p + 1) * 128 + l31 * 4];
                a.u[p] = pk_f16(lo, hi);
            }
            acc = __builtin_amdgcn_mfma_f32_32x32x16_f16(wf.v, a.v, acc, 0, 0, 0);
        }

        // store: col = lane&31 = t ; row d = (reg&3) + 8*(reg>>2) + 4*g
#pragma unroll
        for (int rg = 0; rg < 16; ++rg) {
            const int drow = wv * 32 + (rg & 3) + 8 * (rg >> 2) + 4 * g;
            ob[(size_t)drow * NT + tg + l31] = acc[rg];
        }
    }
}

// ---------------------------------------------------------------------------
// Fallback: exact R13 kernel (130 us known-good) if ws_size is too small.
// ---------------------------------------------------------------------------
__global__ __launch_bounds__(512, 4)
void subject_gemm_fb(const float* __restrict__ x,
                     const int*   __restrict__ subjects,
                     const float* __restrict__ w,
                     float*       __restrict__ out)
{
    __shared__ __align__(16) unsigned char lds[2 * 32 * 512];

    const int tid  = threadIdx.x;
    const int lane = tid & 63;
    const int wv   = tid >> 6;
    const int g    = lane >> 5;
    const int l31  = lane & 31;
    const int b    = blockIdx.y;
    const int t0   = blockIdx.x * 512;

    const int sub = subjects[b];
    const float* __restrict__ wsub = w + (size_t)sub * NC * ND;
    const float* __restrict__ xb   = x + (size_t)b * NC * NT;
    float*       __restrict__ ob   = out + (size_t)b * ND * NT;

    const int dlane = wv * 32 + l31;

    half8 wf[16];
#pragma unroll
    for (int ks = 0; ks < 16; ++ks) {
        float f[8];
#pragma unroll
        for (int j = 0; j < 8; ++j)
            f[j] = wsub[(size_t)(ks * 16 + g * 8 + j) * ND + dlane];
        FragA tmp;
#pragma unroll
        for (int p = 0; p < 4; ++p) tmp.u[p] = pk_f16(f[2 * p], f[2 * p + 1]);
        wf[ks] = tmp.v;
    }

    const int c0 = wv * 32 + g * 16;
    const uint32_t swz      = ((uint32_t)(l31 & 15)) << 4;
    const uint32_t wr_byte0 = (uint32_t)l31 * 512 + (((uint32_t)c0 * 2 +  0) ^ swz);
    const uint32_t wr_byte1 = (uint32_t)l31 * 512 + (((uint32_t)c0 * 2 + 16) ^ swz);
    const uint32_t rd_row   = (uint32_t)l31 * 512;

    const float* xg = xb + (size_t)c0 * NT + t0 + l31;

    float stage[16];
#pragma unroll
    for (int i = 0; i < 16; ++i) stage[i] = xg[(size_t)i * NT];
    {
        uint4 q0, q1;
        q0.x = pk_f16(stage[0],  stage[1]);  q0.y = pk_f16(stage[2],  stage[3]);
        q0.z = pk_f16(stage[4],  stage[5]);  q0.w = pk_f16(stage[6],  stage[7]);
        q1.x = pk_f16(stage[8],  stage[9]);  q1.y = pk_f16(stage[10], stage[11]);
        q1.z = pk_f16(stage[12], stage[13]); q1.w = pk_f16(stage[14], stage[15]);
        *reinterpret_cast<uint4*>(&lds[wr_byte0]) = q0;
        *reinterpret_cast<uint4*>(&lds[wr_byte1]) = q1;
    }
    __syncthreads();

    for (int tile = 0; tile < 16; ++tile) {
        const uint32_t bufoff = (uint32_t)(tile & 1) * 16384;
        if (tile + 1 < 16) {
            const float* src = xg + (size_t)(tile + 1) * BT;
#pragma unroll
            for (int i = 0; i < 16; ++i) stage[i] = src[(size_t)i * NT];
        }
        f32x16 acc = {};
#pragma unroll
        for (int ks = 0; ks < 16; ++ks) {
            const uint32_t colb = ((uint32_t)(ks * 32 + g * 16)) ^ swz;
            FragA a;
            a.q = *reinterpret_cast<const uint4*>(&lds[bufoff + rd_row + colb]);
            acc = __builtin_amdgcn_mfma_f32_32x32x16_f16(wf[ks], a.v, acc, 0, 0, 0);
        }
        const int tcol = t0 + tile * BT;
#pragma unroll
        for (int rg = 0; rg < 16; ++rg) {
            const int drow = wv * 32 + (rg & 3) + 8 * (rg >> 2) + 4 * g;
            ob[(size_t)drow * NT + tcol + l31] = acc[rg];
        }
        if (tile + 1 < 16) {
            const uint32_t nb = (uint32_t)((tile + 1) & 1) * 16384;
            uint4 q0, q1;
            q0.x = pk_f16(stage[0],  stage[1]);  q0.y = pk_f16(stage[2],  stage[3]);
            q0.z = pk_f16(stage[4],  stage[5]);  q0.w = pk_f16(stage[6],  stage[7]);
            q1.x = pk_f16(stage[8],  stage[9]);  q1.y = pk_f16(stage[10], stage[11]);
            q1.z = pk_f16(stage[12], stage[13]); q1.w = pk_f16(stage[14], stage[15]);
            *reinterpret_cast<uint4*>(&lds[nb + wr_byte0]) = q0;
            *reinterpret_cast<uint4*>(&lds[nb + wr_byte1]) = q1;
        }
        __syncthreads();
    }
}

extern "C" void kernel_launch(void* const* d_in, const int* in_sizes, int n_in,
                              void* d_out, int out_size, void* d_ws, size_t ws_size,
                              hipStream_t stream)
{
    const float* x        = (const float*)d_in[0];
    const int*   subjects = (const int*)d_in[1];
    const float* w        = (const float*)d_in[2];
    float*       out      = (float*)d_out;

    const int    S    = in_sizes[2] / (NC * ND);         // 32
    const size_t need = (size_t)S * 8 * 16 * 64 * 16;    // S * 128 KB = 4 MB

    if (ws_size >= need) {
        wprep<<<dim3(8, S), 64, 0, stream>>>(w, (uint4*)d_ws);
        subject_gemm_ws<<<dim3(NCHUNK, NB), 512, 0, stream>>>(
            x, subjects, (const uint4*)d_ws, out);
    } else {
        subject_gemm_fb<<<dim3(8, NB), 512, 0, stream>>>(x, subjects, w, out);
    }
}